// Round 1
// baseline (308.752 us; speedup 1.0000x reference)
//
#include <hip/hip_runtime.h>
#include <cstdint>
#include <cstddef>

#pragma clang fp contract(off)

#define A_N 76725
#define C_N 80
#define CA_N (A_N * C_N)          // 6,138,000
#define MAXDET 200
#define CAP 4096
#define IMG_F 640.0f

// ---------------------------------------------------------------------------
// IoU predicate — exact op sequence of the reference:
//   ix1=max, iy1=max, ix2=min, iy2=min; inter=max(ix2-ix1,0)*max(iy2-iy1,0)
//   iou = inter / (ab + areas - inter);  compare iou > 0.5 (strict).
// NaN (0/0) compares false, matching jnp semantics.
// ---------------------------------------------------------------------------
__device__ __forceinline__ bool iou_gt(float b0, float b1, float b2, float b3, float ab,
                                       float x0, float x1, float x2, float x3, float xa) {
    float ix1 = fmaxf(b0, x0);
    float iy1 = fmaxf(b1, x1);
    float ix2 = fminf(b2, x2);
    float iy2 = fminf(b3, x3);
    float iw = fmaxf(ix2 - ix1, 0.0f);
    float ih = fmaxf(iy2 - iy1, 0.0f);
    float inter = iw * ih;
    float den = ab + xa - inter;
    float iou = inter / den;
    return iou > 0.5f;
}

// ---------------------------------------------------------------------------
// K1: decode + clip boxes.  boxes[a][4] in xyxy.
// ---------------------------------------------------------------------------
__global__ void k_decode(const float* __restrict__ reg,
                         const float* __restrict__ anc,
                         float* __restrict__ boxes) {
    int a = blockIdx.x * blockDim.x + threadIdx.x;
    if (a >= A_N) return;
    float a0 = anc[a * 4 + 0], a1 = anc[a * 4 + 1];
    float a2 = anc[a * 4 + 2], a3 = anc[a * 4 + 3];
    float aw = a2 - a0;
    float ah = a3 - a1;
    float ax = a0 + 0.5f * aw;
    float ay = a1 + 0.5f * ah;
    float r0 = reg[a * 4 + 0], r1 = reg[a * 4 + 1];
    float r2 = reg[a * 4 + 2], r3 = reg[a * 4 + 3];
    float cx = ax + r0 * 0.1f * aw;
    float cy = ay + r1 * 0.1f * ah;
    float w = aw * expf(r2 * 0.2f);
    float h = ah * expf(r3 * 0.2f);
    float x1 = fminf(fmaxf(cx - 0.5f * w, 0.0f), IMG_F);
    float y1 = fminf(fmaxf(cy - 0.5f * h, 0.0f), IMG_F);
    float x2 = fminf(fmaxf(cx + 0.5f * w, 0.0f), IMG_F);
    float y2 = fminf(fmaxf(cy + 0.5f * h, 0.0f), IMG_F);
    boxes[a * 4 + 0] = x1;
    boxes[a * 4 + 1] = y1;
    boxes[a * 4 + 2] = x2;
    boxes[a * 4 + 3] = y2;
}

// ---------------------------------------------------------------------------
// K2: transpose classification [A,C] -> clsT [C,A]  (LDS-tiled 32x32)
// ---------------------------------------------------------------------------
__global__ void k_transpose(const float* __restrict__ cls, float* __restrict__ clsT) {
    __shared__ float tile[32][33];
    int tx = threadIdx.x, ty = threadIdx.y;
    int a = blockIdx.x * 32 + ty;
    int c = blockIdx.y * 32 + tx;
    if (a < A_N && c < C_N) tile[ty][tx] = cls[(size_t)a * C_N + c];
    __syncthreads();
    int c2 = blockIdx.y * 32 + ty;
    int a2 = blockIdx.x * 32 + tx;
    if (c2 < C_N && a2 < A_N) clsT[(size_t)c2 * A_N + a2] = tile[tx][ty];
}

// ---------------------------------------------------------------------------
// K3: per-class greedy NMS.  One block (1024 thr) per class.
// Band-select candidates (descending 0.025-wide score bands), bitonic-sort
// (score desc, idx asc) in LDS, then chunk-of-64 bitmask greedy resolve.
// Writes kept records (count, anchor idx, score) to workspace.
// ---------------------------------------------------------------------------
__global__ __launch_bounds__(1024) void k_nms(const float* __restrict__ clsT,
                                              const float* __restrict__ boxes,
                                              int* __restrict__ kcnt,
                                              int* __restrict__ kidx,
                                              float* __restrict__ kscr) {
    const int c = blockIdx.x;
    const int tid = threadIdx.x;
    const float* col = clsT + (size_t)c * A_N;

    __shared__ unsigned long long keys[CAP];     // 32 KB
    __shared__ float kbox[MAXDET][4];
    __shared__ float karea[MAXDET];
    __shared__ int kIdxL[MAXDET];
    __shared__ float kScrL[MAXDET];
    __shared__ float cbx[64][4];
    __shared__ float car[64];
    __shared__ unsigned int mlo[64], mhi[64];
    __shared__ unsigned char supp[64];
    __shared__ int cntL, keptL;

    int kept = 0;
    float hi = 3.402823466e38f;

    for (int band = 0;; ++band) {
        float lo = 0.975f - 0.025f * (float)band;
        bool last = (lo <= 0.1f);
        float loEff = last ? 0.1f : lo;

        if (tid == 0) cntL = 0;
        __syncthreads();

        // --- band scan + compact -------------------------------------------
        for (int a = tid; a < A_N; a += 1024) {
            float s = col[a];
            if (s > loEff && s <= hi) {
                int p = atomicAdd(&cntL, 1);
                if (p < CAP)
                    keys[p] = ((unsigned long long)__float_as_uint(s) << 32) |
                              (unsigned long long)(0xFFFFFFFFu - (unsigned)a);
            }
        }
        __syncthreads();
        int cnt = cntL < CAP ? cntL : CAP;

        // --- pad to pow2 and bitonic sort (descending) ---------------------
        int n2 = 64;
        while (n2 < cnt) n2 <<= 1;
        for (int i = cnt + tid; i < n2; i += 1024) keys[i] = 0ull;
        __syncthreads();
        for (int k = 2; k <= n2; k <<= 1) {
            for (int j = k >> 1; j > 0; j >>= 1) {
                for (int i = tid; i < n2; i += 1024) {
                    int ixj = i ^ j;
                    if (ixj > i) {
                        unsigned long long u = keys[i], v = keys[ixj];
                        bool up = ((i & k) == 0);
                        if (up ? (u < v) : (u > v)) { keys[i] = v; keys[ixj] = u; }
                    }
                }
                __syncthreads();
            }
        }

        // --- chunk-of-64 greedy resolve ------------------------------------
        for (int cs = 0; cs < cnt && kept < MAXDET; cs += 64) {
            int nc = (cnt - cs < 64) ? (cnt - cs) : 64;
            float rb0 = 0, rb1 = 0, rb2 = 0, rb3 = 0, rar = 0, rsc = 0;
            int rix = 0;
            if (tid < 64) {
                mlo[tid] = 0;
                mhi[tid] = 0;
                supp[tid] = (tid < nc) ? 0 : 1;
                if (tid < nc) {
                    unsigned long long key = keys[cs + tid];
                    rix = (int)(0xFFFFFFFFu - (unsigned)(key & 0xFFFFFFFFull));
                    rsc = __uint_as_float((unsigned)(key >> 32));
                    rb0 = boxes[rix * 4 + 0];
                    rb1 = boxes[rix * 4 + 1];
                    rb2 = boxes[rix * 4 + 2];
                    rb3 = boxes[rix * 4 + 3];
                    rar = (rb2 - rb0) * (rb3 - rb1);
                    cbx[tid][0] = rb0; cbx[tid][1] = rb1;
                    cbx[tid][2] = rb2; cbx[tid][3] = rb3;
                    car[tid] = rar;
                }
            }
            __syncthreads();

            // suppression by already-kept boxes (64 cands x 16 threads each)
            {
                int i = tid >> 4, jl = tid & 15;
                if (i < nc) {
                    float x0 = cbx[i][0], x1 = cbx[i][1];
                    float x2 = cbx[i][2], x3 = cbx[i][3], xa = car[i];
                    bool s = false;
                    for (int j = jl; j < kept; j += 16) {
                        if (iou_gt(kbox[j][0], kbox[j][1], kbox[j][2], kbox[j][3],
                                   karea[j], x0, x1, x2, x3, xa)) { s = true; break; }
                    }
                    if (s) supp[i] = 1;
                }
            }
            // intra-chunk suppression matrix: mask[i] bit j (j>i)
            {
                int i = tid & 63, jb = tid >> 6;
                if (i < nc) {
                    float b0 = cbx[i][0], b1 = cbx[i][1];
                    float b2 = cbx[i][2], b3 = cbx[i][3], ba = car[i];
                    unsigned int l32 = 0, h32 = 0;
                    for (int j = jb; j < nc; j += 16) {
                        if (j > i) {
                            if (iou_gt(b0, b1, b2, b3, ba,
                                       cbx[j][0], cbx[j][1], cbx[j][2], cbx[j][3], car[j])) {
                                if (j < 32) l32 |= 1u << j;
                                else        h32 |= 1u << (j - 32);
                            }
                        }
                    }
                    if (l32) atomicOr(&mlo[i], l32);
                    if (h32) atomicOr(&mhi[i], h32);
                }
            }
            __syncthreads();

            // wave-0 serial resolve (ballot over 64 lanes)
            if (tid < 64) {
                int lane = tid;
                bool alive = (lane < nc) && (supp[lane] == 0);
                unsigned int myLo = mlo[lane], myHi = mhi[lane];
                int kc = kept;
                while (kc < MAXDET) {
                    unsigned long long av = __ballot(alive);
                    if (av == 0ull) break;
                    int i = (int)__builtin_ctzll(av);
                    unsigned int plo = (unsigned)__shfl((int)myLo, i, 64);
                    unsigned int phi = (unsigned)__shfl((int)myHi, i, 64);
                    unsigned long long mi = ((unsigned long long)phi << 32) | plo;
                    if (lane == i) {
                        kbox[kc][0] = rb0; kbox[kc][1] = rb1;
                        kbox[kc][2] = rb2; kbox[kc][3] = rb3;
                        karea[kc] = rar;
                        kIdxL[kc] = rix;
                        kScrL[kc] = rsc;
                        alive = false;
                    }
                    if ((mi >> lane) & 1ull) alive = false;
                    kc++;
                }
                if (lane == 0) keptL = kc;
            }
            __syncthreads();
            kept = keptL;
        }

        if (kept >= MAXDET || last) break;
        hi = loEff;
    }

    if (tid == 0) kcnt[c] = kept;
    for (int i = tid; i < kept; i += 1024) {
        kidx[c * MAXDET + i] = kIdxL[i];
        kscr[c * MAXDET + i] = kScrL[i];
    }
}

// ---------------------------------------------------------------------------
// K4: fill all outputs with defaults (scores 0, labels -1, boxes 0, keep 0)
// ---------------------------------------------------------------------------
__global__ void k_fill(float4* __restrict__ out4) {
    int i = blockIdx.x * blockDim.x + threadIdx.x;
    const int n4 = (7 * CA_N) / 4;
    if (i >= n4) return;
    const int lab_lo = CA_N / 4;
    const int lab_hi = (2 * CA_N) / 4;
    float v = (i >= lab_lo && i < lab_hi) ? -1.0f : 0.0f;
    out4[i] = make_float4(v, v, v, v);
}

// ---------------------------------------------------------------------------
// K5: scatter kept entries into outputs
// ---------------------------------------------------------------------------
__global__ void k_scatter(const int* __restrict__ kcnt, const int* __restrict__ kidx,
                          const float* __restrict__ kscr, const float* __restrict__ boxes,
                          float* __restrict__ out) {
    int c = blockIdx.x, t = threadIdx.x;
    int k = kcnt[c];
    for (int i = t; i < k; i += blockDim.x) {
        int a = kidx[c * MAXDET + i];
        float s = kscr[c * MAXDET + i];
        size_t base = (size_t)c * A_N + (size_t)a;
        out[base] = s;                                   // final_scores
        out[(size_t)CA_N + base] = (float)c;             // final_labels
        size_t bo = (size_t)2 * CA_N + base * 4;         // final_boxes
        out[bo + 0] = boxes[a * 4 + 0];
        out[bo + 1] = boxes[a * 4 + 1];
        out[bo + 2] = boxes[a * 4 + 2];
        out[bo + 3] = boxes[a * 4 + 3];
        out[(size_t)6 * CA_N + base] = 1.0f;             // keep
    }
}

extern "C" void kernel_launch(void* const* d_in, const int* in_sizes, int n_in,
                              void* d_out, int out_size, void* d_ws, size_t ws_size,
                              hipStream_t stream) {
    const float* cls = (const float*)d_in[0];   // [1, A, C]
    const float* reg = (const float*)d_in[1];   // [1, A, 4]
    const float* anc = (const float*)d_in[2];   // [A, 4]
    float* out = (float*)d_out;

    // workspace layout (small, ~1.4 MB)
    float* boxes = (float*)d_ws;                       // 4*A floats
    int* kcnt = (int*)(boxes + 4 * A_N);               // C ints
    int* kidx = kcnt + C_N;                            // C*MAXDET ints
    float* kscr = (float*)(kidx + C_N * MAXDET);       // C*MAXDET floats

    // clsT staged in the (large) boxes region of d_out; overwritten by k_fill
    // AFTER k_nms has consumed it (stream-ordered).
    float* clsT = out + (size_t)2 * CA_N;              // C*A floats fits in 4*C*A

    k_decode<<<(A_N + 255) / 256, 256, 0, stream>>>(reg, anc, boxes);

    dim3 tgrid((A_N + 31) / 32, (C_N + 31) / 32);
    k_transpose<<<tgrid, dim3(32, 32), 0, stream>>>(cls, clsT);

    k_nms<<<C_N, 1024, 0, stream>>>(clsT, boxes, kcnt, kidx, kscr);

    const int n4 = (7 * CA_N) / 4;
    k_fill<<<(n4 + 255) / 256, 256, 0, stream>>>((float4*)d_out);

    k_scatter<<<C_N, 256, 0, stream>>>(kcnt, kidx, kscr, boxes, out);
}

// Round 2
// 280.319 us; speedup vs baseline: 1.1014x; 1.1014x over previous
//
#include <hip/hip_runtime.h>
#include <cstdint>
#include <cstddef>

#pragma clang fp contract(off)

#define A_N 76725
#define C_N 80
#define CA_N (A_N * C_N)          // 6,138,000
#define MAXDET 200
#define CAP 4096
#define IMG_F 640.0f
#define THR0 0.975f
#define CNT_STRIDE 32             // ints; 128 B per counter -> one L2 line each

// ---------------------------------------------------------------------------
// IoU predicate — exact op sequence of the reference.
// ---------------------------------------------------------------------------
__device__ __forceinline__ bool iou_gt(float b0, float b1, float b2, float b3, float ab,
                                       float x0, float x1, float x2, float x3, float xa) {
    float ix1 = fmaxf(b0, x0);
    float iy1 = fmaxf(b1, x1);
    float ix2 = fminf(b2, x2);
    float iy2 = fminf(b3, x3);
    float iw = fmaxf(ix2 - ix1, 0.0f);
    float ih = fmaxf(iy2 - iy1, 0.0f);
    float inter = iw * ih;
    float den = ab + xa - inter;
    float iou = inter / den;
    return iou > 0.5f;
}

__device__ __forceinline__ float band_lo(int b) {
    return 0.975f - 0.025f * (float)b;   // b=0 -> 0.975f exactly (matches THR0)
}

// ---------------------------------------------------------------------------
// K1: fused decode + candidate select.
//   threads i < A_N      : decode+clip box i
//   threads i < CA_N     : read cls[i] ([A,C] layout, coalesced); if > THR0,
//                          push key into per-class buffer (global atomic slot).
// ---------------------------------------------------------------------------
__global__ __launch_bounds__(256) void k_prep(const float* __restrict__ cls,
                                              const float* __restrict__ reg,
                                              const float* __restrict__ anc,
                                              float* __restrict__ boxes,
                                              int* __restrict__ gcnt,
                                              unsigned long long* __restrict__ gkeys) {
    int i = blockIdx.x * 256 + threadIdx.x;
    if (i < A_N) {
        float a0 = anc[i * 4 + 0], a1 = anc[i * 4 + 1];
        float a2 = anc[i * 4 + 2], a3 = anc[i * 4 + 3];
        float aw = a2 - a0;
        float ah = a3 - a1;
        float ax = a0 + 0.5f * aw;
        float ay = a1 + 0.5f * ah;
        float r0 = reg[i * 4 + 0], r1 = reg[i * 4 + 1];
        float r2 = reg[i * 4 + 2], r3 = reg[i * 4 + 3];
        float cx = ax + r0 * 0.1f * aw;
        float cy = ay + r1 * 0.1f * ah;
        float w = aw * expf(r2 * 0.2f);
        float h = ah * expf(r3 * 0.2f);
        float x1 = fminf(fmaxf(cx - 0.5f * w, 0.0f), IMG_F);
        float y1 = fminf(fmaxf(cy - 0.5f * h, 0.0f), IMG_F);
        float x2 = fminf(fmaxf(cx + 0.5f * w, 0.0f), IMG_F);
        float y2 = fminf(fmaxf(cy + 0.5f * h, 0.0f), IMG_F);
        boxes[i * 4 + 0] = x1;
        boxes[i * 4 + 1] = y1;
        boxes[i * 4 + 2] = x2;
        boxes[i * 4 + 3] = y2;
    }
    if (i < CA_N) {
        float s = cls[i];
        if (s > THR0) {
            int c = i % C_N;
            unsigned a = (unsigned)(i / C_N);
            int p = atomicAdd(&gcnt[c * CNT_STRIDE], 1);
            if (p < CAP)
                gkeys[(size_t)c * CAP + p] =
                    ((unsigned long long)__float_as_uint(s) << 32) |
                    (unsigned long long)(0xFFFFFFFFu - a);
        }
    }
}

// ---------------------------------------------------------------------------
// K2: fill all outputs with defaults (scores 0, labels -1, boxes 0, keep 0)
// ---------------------------------------------------------------------------
__global__ __launch_bounds__(256) void k_fill(float4* __restrict__ out4) {
    int i = blockIdx.x * 256 + threadIdx.x;
    const int n4 = (7 * CA_N) / 4;
    if (i >= n4) return;
    const int lab_lo = CA_N / 4;
    const int lab_hi = (2 * CA_N) / 4;
    float v = (i >= lab_lo && i < lab_hi) ? -1.0f : 0.0f;
    out4[i] = make_float4(v, v, v, v);
}

// ---------------------------------------------------------------------------
// K3: per-class greedy NMS + inline scatter.  One block (1024 thr) per class.
// Band 0 candidates come precompacted from gkeys; fallback bands (rare) scan
// the cls column strided.  Ends by writing kept entries straight to d_out
// (k_fill has already written defaults — stream-ordered).
// ---------------------------------------------------------------------------
__global__ __launch_bounds__(1024) void k_nms(const float* __restrict__ cls,
                                              const float* __restrict__ boxes,
                                              const int* __restrict__ gcnt,
                                              const unsigned long long* __restrict__ gkeys,
                                              float* __restrict__ out) {
    const int c = blockIdx.x;
    const int tid = threadIdx.x;

    __shared__ unsigned long long keys[CAP];     // 32 KB
    __shared__ float kbox[MAXDET][4];
    __shared__ float karea[MAXDET];
    __shared__ int kIdxL[MAXDET];
    __shared__ float kScrL[MAXDET];
    __shared__ float cbx[64][4];
    __shared__ float car[64];
    __shared__ unsigned int mlo[64], mhi[64];
    __shared__ unsigned char supp[64];
    __shared__ int cntL, keptL;

    int kept = 0;

    for (int band = 0;; ++band) {
        int cnt;
        bool last = false;
        if (band == 0) {
            cnt = gcnt[c * CNT_STRIDE];
            if (cnt > CAP) cnt = CAP;
            for (int i = tid; i < cnt; i += 1024)
                keys[i] = gkeys[(size_t)c * CAP + i];
            __syncthreads();
        } else {
            float hiB = band_lo(band - 1);
            float lo = band_lo(band);
            last = (lo <= 0.1f);
            float loEff = last ? 0.1f : lo;
            if (tid == 0) cntL = 0;
            __syncthreads();
            for (int a = tid; a < A_N; a += 1024) {
                float s = cls[(size_t)a * C_N + c];
                if (s > loEff && s <= hiB) {
                    int p = atomicAdd(&cntL, 1);
                    if (p < CAP)
                        keys[p] = ((unsigned long long)__float_as_uint(s) << 32) |
                                  (unsigned long long)(0xFFFFFFFFu - (unsigned)a);
                }
            }
            __syncthreads();
            cnt = cntL < CAP ? cntL : CAP;
        }

        // --- pad to pow2 and bitonic sort (descending) ---------------------
        int n2 = 64;
        while (n2 < cnt) n2 <<= 1;
        for (int i = cnt + tid; i < n2; i += 1024) keys[i] = 0ull;
        __syncthreads();
        for (int k = 2; k <= n2; k <<= 1) {
            for (int j = k >> 1; j > 0; j >>= 1) {
                for (int i = tid; i < n2; i += 1024) {
                    int ixj = i ^ j;
                    if (ixj > i) {
                        unsigned long long u = keys[i], v = keys[ixj];
                        bool up = ((i & k) == 0);
                        if (up ? (u < v) : (u > v)) { keys[i] = v; keys[ixj] = u; }
                    }
                }
                __syncthreads();
            }
        }

        // --- chunk-of-64 greedy resolve ------------------------------------
        for (int cs = 0; cs < cnt && kept < MAXDET; cs += 64) {
            int nc = (cnt - cs < 64) ? (cnt - cs) : 64;
            float rb0 = 0, rb1 = 0, rb2 = 0, rb3 = 0, rar = 0, rsc = 0;
            int rix = 0;
            if (tid < 64) {
                mlo[tid] = 0;
                mhi[tid] = 0;
                supp[tid] = (tid < nc) ? 0 : 1;
                if (tid < nc) {
                    unsigned long long key = keys[cs + tid];
                    rix = (int)(0xFFFFFFFFu - (unsigned)(key & 0xFFFFFFFFull));
                    rsc = __uint_as_float((unsigned)(key >> 32));
                    rb0 = boxes[rix * 4 + 0];
                    rb1 = boxes[rix * 4 + 1];
                    rb2 = boxes[rix * 4 + 2];
                    rb3 = boxes[rix * 4 + 3];
                    rar = (rb2 - rb0) * (rb3 - rb1);
                    cbx[tid][0] = rb0; cbx[tid][1] = rb1;
                    cbx[tid][2] = rb2; cbx[tid][3] = rb3;
                    car[tid] = rar;
                }
            }
            __syncthreads();

            // suppression by already-kept boxes (64 cands x 16 threads each)
            {
                int i = tid >> 4, jl = tid & 15;
                if (i < nc) {
                    float x0 = cbx[i][0], x1 = cbx[i][1];
                    float x2 = cbx[i][2], x3 = cbx[i][3], xa = car[i];
                    bool s = false;
                    for (int j = jl; j < kept; j += 16) {
                        if (iou_gt(kbox[j][0], kbox[j][1], kbox[j][2], kbox[j][3],
                                   karea[j], x0, x1, x2, x3, xa)) { s = true; break; }
                    }
                    if (s) supp[i] = 1;
                }
            }
            // intra-chunk suppression matrix: mask[i] bit j (j>i)
            {
                int i = tid & 63, jb = tid >> 6;
                if (i < nc) {
                    float b0 = cbx[i][0], b1 = cbx[i][1];
                    float b2 = cbx[i][2], b3 = cbx[i][3], ba = car[i];
                    unsigned int l32 = 0, h32 = 0;
                    for (int j = jb; j < nc; j += 16) {
                        if (j > i) {
                            if (iou_gt(b0, b1, b2, b3, ba,
                                       cbx[j][0], cbx[j][1], cbx[j][2], cbx[j][3], car[j])) {
                                if (j < 32) l32 |= 1u << j;
                                else        h32 |= 1u << (j - 32);
                            }
                        }
                    }
                    if (l32) atomicOr(&mlo[i], l32);
                    if (h32) atomicOr(&mhi[i], h32);
                }
            }
            __syncthreads();

            // wave-0 serial resolve (ballot over 64 lanes)
            if (tid < 64) {
                int lane = tid;
                bool alive = (lane < nc) && (supp[lane] == 0);
                unsigned int myLo = mlo[lane], myHi = mhi[lane];
                int kc = kept;
                while (kc < MAXDET) {
                    unsigned long long av = __ballot(alive);
                    if (av == 0ull) break;
                    int i = (int)__builtin_ctzll(av);
                    unsigned int plo = (unsigned)__shfl((int)myLo, i, 64);
                    unsigned int phi = (unsigned)__shfl((int)myHi, i, 64);
                    unsigned long long mi = ((unsigned long long)phi << 32) | plo;
                    if (lane == i) {
                        kbox[kc][0] = rb0; kbox[kc][1] = rb1;
                        kbox[kc][2] = rb2; kbox[kc][3] = rb3;
                        karea[kc] = rar;
                        kIdxL[kc] = rix;
                        kScrL[kc] = rsc;
                        alive = false;
                    }
                    if ((mi >> lane) & 1ull) alive = false;
                    kc++;
                }
                if (lane == 0) keptL = kc;
            }
            __syncthreads();
            kept = keptL;
        }

        if (kept >= MAXDET || last) break;
    }

    // --- inline scatter of kept entries (k_fill already wrote defaults) ----
    for (int i = tid; i < kept; i += 1024) {
        int a = kIdxL[i];
        size_t base = (size_t)c * A_N + (size_t)a;
        out[base] = kScrL[i];                            // final_scores
        out[(size_t)CA_N + base] = (float)c;             // final_labels
        size_t bo = (size_t)2 * CA_N + base * 4;         // final_boxes
        out[bo + 0] = kbox[i][0];
        out[bo + 1] = kbox[i][1];
        out[bo + 2] = kbox[i][2];
        out[bo + 3] = kbox[i][3];
        out[(size_t)6 * CA_N + base] = 1.0f;             // keep
    }
}

extern "C" void kernel_launch(void* const* d_in, const int* in_sizes, int n_in,
                              void* d_out, int out_size, void* d_ws, size_t ws_size,
                              hipStream_t stream) {
    const float* cls = (const float*)d_in[0];   // [1, A, C]
    const float* reg = (const float*)d_in[1];   // [1, A, 4]
    const float* anc = (const float*)d_in[2];   // [A, 4]
    float* out = (float*)d_out;

    // workspace layout (~7.6 MB)
    int* gcnt = (int*)d_ws;                               // C * CNT_STRIDE ints (padded)
    float* boxes = (float*)(gcnt + C_N * CNT_STRIDE);     // 4*A floats
    unsigned long long* gkeys =
        (unsigned long long*)(boxes + 4 * A_N);           // C*CAP u64

    hipMemsetAsync(gcnt, 0, C_N * CNT_STRIDE * sizeof(int), stream);

    k_prep<<<(CA_N + 255) / 256, 256, 0, stream>>>(cls, reg, anc, boxes, gcnt, gkeys);

    const int n4 = (7 * CA_N) / 4;
    k_fill<<<(n4 + 255) / 256, 256, 0, stream>>>((float4*)d_out);

    k_nms<<<C_N, 1024, 0, stream>>>(cls, boxes, gcnt, gkeys, out);
}